// Round 2
// baseline (2207.656 us; speedup 1.0000x reference)
//
#include <hip/hip_runtime.h>
#include <cstdint>
#include <cstddef>

#define SEQ    2048
#define NB     4
#define DM     1024
#define DI     2048
#define MTOK   (NB*SEQ)   // 8192

typedef unsigned short u16;
typedef __attribute__((ext_vector_type(8))) short  short8;
typedef __attribute__((ext_vector_type(4))) float  f32x4;
typedef __attribute__((ext_vector_type(4))) unsigned short us4;

__device__ __forceinline__ float b2f(u16 u){ union{unsigned i; float f;} c; c.i=((unsigned)u)<<16; return c.f; }
__device__ __forceinline__ u16 f2b(float f){
  union{float f; unsigned u;} c; c.f=f;
  unsigned r = c.u + 0x7fffu + ((c.u>>16)&1u);
  return (u16)(r>>16);
}

__device__ __forceinline__ void gload_lds16(const void* g, void* l){
  __builtin_amdgcn_global_load_lds((const __attribute__((address_space(1))) void*)g,
                                   (__attribute__((address_space(3))) void*)l, 16, 0, 0);
}

// ---------------- f32 -> bf16 conversion (8 elements/thread) ----------------
__global__ __launch_bounds__(256) void cvt_k(const float* __restrict__ in,
                                             u16* __restrict__ out, int n8){
  const int i = blockIdx.x*256 + threadIdx.x;
  if (i >= n8) return;
  const f32x4 a = ((const f32x4*)in)[2*i];
  const f32x4 b = ((const f32x4*)in)[2*i+1];
  short8 r;
  #pragma unroll
  for (int e=0;e<4;e++){ r[e] = (short)f2b(a[e]); r[e+4] = (short)f2b(b[e]); }
  ((short8*)out)[i] = r;
}

// ---------------- x_proj_w (96,2048) f32 -> padded (128,2048) bf16 ----------------
__global__ __launch_bounds__(256) void padcvt_k(const float* __restrict__ in,
                                                u16* __restrict__ out){
  const int i = blockIdx.x*256 + threadIdx.x;   // 32768 threads, 8 elems each
  const int row = (i*8) >> 11;
  short8 r;
  if (row < 96){
    const f32x4 a = ((const f32x4*)in)[2*i];
    const f32x4 b = ((const f32x4*)in)[2*i+1];
    #pragma unroll
    for (int e=0;e<4;e++){ r[e] = (short)f2b(a[e]); r[e+4] = (short)f2b(b[e]); }
  } else {
    #pragma unroll
    for (int e=0;e<8;e++) r[e] = 0;
  }
  ((short8*)out)[i] = r;
}

// ---------------- generic NT GEMM: C[M,N] = X[M,K] * W[N,K]^T (bf16 in) ----------------
// EPI: 0 = store bf16; 1 = store f32; 2 = +bias,softplus -> bf16;
//      3 = +bias,gelu(exact) -> bf16; 4 = +bias -> f32
template<int EPI>
__global__ __launch_bounds__(256) void gemm_bt(
    const u16* __restrict__ X, int lda,
    const u16* __restrict__ W,
    const float* __restrict__ bias,
    void* __restrict__ Cout,
    int M, int N, int K)
{
  __shared__ __align__(16) u16 As[128*64];
  __shared__ __align__(16) u16 Bs[128*64];
  const int tid  = threadIdx.x;
  const int lane = tid & 63;
  const int wv   = tid >> 6;
  const int wr   = wv >> 1, wc = wv & 1;
  const int bm0  = blockIdx.y * 128;
  const int bn0  = blockIdx.x * 128;
  const int r0   = tid >> 3;          // 0..31
  const int c8   = (tid & 7) << 3;    // element offset 0..56

  f32x4 acc[4][4];
  #pragma unroll
  for (int i=0;i<4;i++)
    #pragma unroll
    for (int j=0;j<4;j++){ f32x4 z = {0.f,0.f,0.f,0.f}; acc[i][j] = z; }

  const int lrow = lane & 15;
  const int lko  = (lane >> 4) << 3;

  for (int kt = 0; kt < K; kt += 64) {
    #pragma unroll
    for (int c = 0; c < 4; ++c) {
      const int row = c*32 + r0;
      gload_lds16(X + (size_t)(bm0+row)*lda + kt + c8, &As[row*64 + c8]);
      gload_lds16(W + (size_t)(bn0+row)*K   + kt + c8, &Bs[row*64 + c8]);
    }
    __syncthreads();
    #pragma unroll
    for (int kk = 0; kk < 2; ++kk) {
      short8 af[4], bf[4];
      #pragma unroll
      for (int i=0;i<4;i++) af[i] = *(const short8*)&As[(wr*64 + i*16 + lrow)*64 + kk*32 + lko];
      #pragma unroll
      for (int j=0;j<4;j++) bf[j] = *(const short8*)&Bs[(wc*64 + j*16 + lrow)*64 + kk*32 + lko];
      #pragma unroll
      for (int i=0;i<4;i++)
        #pragma unroll
        for (int j=0;j<4;j++)
          acc[i][j] = __builtin_amdgcn_mfma_f32_16x16x32_bf16(af[i], bf[j], acc[i][j], 0, 0, 0);
    }
    __syncthreads();
  }

  const int rbase = bm0 + wr*64 + ((lane>>4)<<2);
  const int cbase = bn0 + wc*64 + (lane & 15);
  #pragma unroll
  for (int i=0;i<4;i++) {
    #pragma unroll
    for (int j=0;j<4;j++) {
      const int col = cbase + j*16;
      float bval = 0.f;
      if constexpr (EPI >= 2) bval = bias[col];
      #pragma unroll
      for (int r=0;r<4;r++) {
        const int row = rbase + i*16 + r;
        const float v = acc[i][j][r];
        const size_t oid = (size_t)row*N + col;
        if constexpr (EPI == 0) {
          ((u16*)Cout)[oid] = f2b(v);
        } else if constexpr (EPI == 1) {
          ((float*)Cout)[oid] = v;
        } else if constexpr (EPI == 2) {
          float xv = v + bval;
          float sp = (xv > 20.f) ? xv : log1pf(__expf(xv));
          ((u16*)Cout)[oid] = f2b(sp);
        } else if constexpr (EPI == 3) {
          float xv = v + bval;
          float g = 0.5f*xv*(1.f + erff(xv*0.70710678118f));
          ((u16*)Cout)[oid] = f2b(g);
        } else {
          ((float*)Cout)[oid] = v + bval;
        }
      }
    }
  }
}

// ---------------- causal depthwise conv (width 4) + SiLU ----------------
// reads u = xz[:, 0:2048] (bf16); conv weights/bias are f32; writes bf16
__global__ __launch_bounds__(256) void conv_silu_k(
    const u16* __restrict__ xz, const float* __restrict__ cw,
    const float* __restrict__ cb, u16* __restrict__ uout)
{
  const int m  = blockIdx.x;          // token index
  const int t  = m & (SEQ-1);
  const int d8 = threadIdx.x << 3;    // 8 channels per thread
  float w[4][8];                      // [tap][chan]
  const float* wp = cw + (size_t)d8*4;
  #pragma unroll
  for (int q=0;q<8;q++){
    f32x4 v = ((const f32x4*)wp)[q];
    #pragma unroll
    for (int e=0;e<4;e++){ int li=q*4+e; w[li&3][li>>2]=v[e]; }
  }
  float acc[8];
  {
    f32x4 b0 = ((const f32x4*)&cb[d8])[0];
    f32x4 b1 = ((const f32x4*)&cb[d8])[1];
    #pragma unroll
    for (int e=0;e<4;e++){ acc[e]=b0[e]; acc[e+4]=b1[e]; }
  }
  #pragma unroll
  for (int j=0;j<4;j++){
    const int tt = t - 3 + j;
    if (tt >= 0){
      short8 v = *(const short8*)&xz[(size_t)(m-3+j)*4096 + d8];
      #pragma unroll
      for (int e=0;e<8;e++) acc[e] = fmaf(b2f((u16)v[e]), w[j][e], acc[e]);
    }
  }
  short8 r;
  #pragma unroll
  for (int e=0;e<8;e++){
    float x = acc[e];
    r[e] = (short)f2b(x / (1.f + __expf(-x)));
  }
  *(short8*)&uout[(size_t)m*2048 + d8] = r;
}

// ---------------- selective scan, fused +u*D and *silu(z) ----------------
// 16 lanes per (b,d) channel; delta_y holds delta on input, ygated on output
__global__ __launch_bounds__(256) void scan_k(
    u16* delta_y,
    const u16* __restrict__ ucv,
    const u16* __restrict__ xz,
    const u16* __restrict__ xdbl,
    const float* __restrict__ A_log,
    const float* __restrict__ Dp)
{
  const int gid = blockIdx.x*256 + threadIdx.x;
  const int n  = gid & 15;
  const int ch = gid >> 4;
  const int d  = ch & (DI-1);
  const int b  = ch >> 11;
  const float A  = -__expf(A_log[d*16 + n]);
  const float Dd = Dp[d];
  float h = 0.f;
  size_t id  = (size_t)b*SEQ*DI + d;
  size_t ixd = (size_t)b*SEQ*128;
  size_t iz  = (size_t)b*SEQ*4096 + DI + d;
  for (int t=0; t<SEQ; ++t) {
    const float delta = b2f(delta_y[id]);
    const float u  = b2f(ucv[id]);
    const float Bv = b2f(xdbl[ixd + 64 + n]);
    const float Cv = b2f(xdbl[ixd + 80 + n]);
    const float dA = __expf(delta * A);
    h = fmaf(dA, h, delta*u*Bv);
    float p = h * Cv;
    p += __shfl_xor(p, 1);
    p += __shfl_xor(p, 2);
    p += __shfl_xor(p, 4);
    p += __shfl_xor(p, 8);
    if (n == 0) {
      const float z = b2f(xz[iz]);
      float y = fmaf(u, Dd, p);
      y *= z / (1.f + __expf(-z));
      delta_y[id] = f2b(y);
    }
    id += DI; ixd += 128; iz += 4096;
  }
}

// ---------------- out = rmsnorm(a_f32 + res) * w  (row=1024) ----------------
// RES_BF: residual is bf16 (else f32); OUT_BF: output bf16 (else f32)
template<bool RES_BF, bool OUT_BF>
__global__ __launch_bounds__(256) void add_rms_k(
    const float* __restrict__ a, const void* __restrict__ res,
    const float* __restrict__ wgt, void* __restrict__ out)
{
  const int row = blockIdx.x;
  const int tid = threadIdx.x;
  const size_t base = (size_t)row*DM + tid*4;
  const f32x4 av = *(const f32x4*)&a[base];
  const f32x4 wv = *(const f32x4*)&wgt[tid*4];
  float v[4]; float ss = 0.f;
  if constexpr (RES_BF) {
    const us4 rv = *(const us4*)&((const u16*)res)[base];
    #pragma unroll
    for (int j=0;j<4;j++){ v[j] = av[j] + b2f(rv[j]); ss = fmaf(v[j], v[j], ss); }
  } else {
    const f32x4 rv = *(const f32x4*)&((const float*)res)[base];
    #pragma unroll
    for (int j=0;j<4;j++){ v[j] = av[j] + rv[j]; ss = fmaf(v[j], v[j], ss); }
  }
  #pragma unroll
  for (int off=32; off>=1; off>>=1) ss += __shfl_xor(ss, off);
  __shared__ float sred[4];
  if ((tid & 63) == 0) sred[tid>>6] = ss;
  __syncthreads();
  const float tot = sred[0]+sred[1]+sred[2]+sred[3];
  const float rs = rsqrtf(tot * (1.f/1024.f) + 1e-12f);
  if constexpr (OUT_BF) {
    us4 ov;
    #pragma unroll
    for (int j=0;j<4;j++) ov[j] = (unsigned short)f2b(v[j] * rs * wv[j]);
    *(us4*)&((u16*)out)[base] = ov;
  } else {
    f32x4 ov;
    #pragma unroll
    for (int j=0;j<4;j++) ov[j] = v[j] * rs * wv[j];
    *(f32x4*)&((float*)out)[base] = ov;
  }
}

extern "C" void kernel_launch(void* const* d_in, const int* in_sizes, int n_in,
                              void* d_out, int out_size, void* d_ws, size_t ws_size,
                              hipStream_t stream) {
  (void)in_sizes; (void)n_in; (void)out_size; (void)ws_size;
  const float* x_in  = (const float*)d_in[0];
  const float* w_inp = (const float*)d_in[1];
  const float* conv_w= (const float*)d_in[2];
  const float* conv_b= (const float*)d_in[3];
  const float* w_xp  = (const float*)d_in[4];
  const float* w_dt  = (const float*)d_in[5];
  const float* b_dt  = (const float*)d_in[6];
  const float* A_log = (const float*)d_in[7];
  const float* Dp    = (const float*)d_in[8];
  const float* w_out = (const float*)d_in[9];
  const float* norm_w= (const float*)d_in[10];
  const float* w_f1  = (const float*)d_in[11];
  const float* b_f1  = (const float*)d_in[12];
  const float* w_f2  = (const float*)d_in[13];
  const float* b_f2  = (const float*)d_in[14];
  const float* norm2 = (const float*)d_in[15];

  char* ws = (char*)d_ws;
  size_t off = 0;
  auto alloc = [&](size_t bytes){ void* p = ws + off; off += (bytes + 255) & ~255ull; return p; };
  u16*   xz   = (u16*)  alloc((size_t)MTOK*4096*2);  // xz, later ffn hidden (67MB)
  u16*   ucv  = (u16*)  alloc((size_t)MTOK*2048*2);  // (33.6MB) later aliased by hbuf
  u16*   xdbl = (u16*)  alloc((size_t)MTOK*128*2);
  u16*   dly  = (u16*)  alloc((size_t)MTOK*2048*2);  // delta, then ygated in place
  float* tmp  = (float*)alloc((size_t)MTOK*1024*4);  // (33.6MB) first used step 11
  u16*   wA   = (u16*)  alloc((size_t)4096*1024*2);  // reused weight slot
  u16*   wpad = (u16*)  alloc((size_t)128*2048*2);
  u16*   wdt  = (u16*)  alloc((size_t)2048*64*2);
  u16*   wout = (u16*)  alloc((size_t)1024*2048*2);
  u16*   xbf  = (u16*)tmp;   // x bf16, dead before tmp is written
  u16*   hbuf = ucv;         // h bf16, born after ucv's last read

  // --- convert f32 operands feeding MFMA to bf16 ---
  cvt_k<<<4096, 256, 0, stream>>>(x_in,  xbf, MTOK*DM/8);
  cvt_k<<<2048, 256, 0, stream>>>(w_inp, wA,  (2*DI*DM)/8);
  padcvt_k<<<128, 256, 0, stream>>>(w_xp, wpad);
  cvt_k<<<64,   256, 0, stream>>>(w_dt,  wdt, (DI*64)/8);
  cvt_k<<<1024, 256, 0, stream>>>(w_out, wout,(DM*DI)/8);

  // 1. in_proj: xz = x @ in_proj_w^T   (M=8192,N=4096,K=1024)
  gemm_bt<0><<<dim3(32,64), 256, 0, stream>>>(xbf, 1024, wA, nullptr, xz, MTOK, 4096, 1024);
  // 2. causal dwconv + silu -> ucv
  conv_silu_k<<<MTOK, 256, 0, stream>>>(xz, conv_w, conv_b, ucv);
  // 3. x_proj: xdbl = ucv @ wpad^T     (N=128,K=2048)
  gemm_bt<0><<<dim3(1,64), 256, 0, stream>>>(ucv, 2048, wpad, nullptr, xdbl, MTOK, 128, 2048);
  // 4. dt_proj + softplus -> delta     (N=2048,K=64; X = xdbl[:, :64], lda=128)
  gemm_bt<2><<<dim3(16,64), 256, 0, stream>>>(xdbl, 128, wdt, b_dt, dly, MTOK, 2048, 64);
  // 5. selective scan (fused +u*D, *silu(z)) -> ygated in dly
  scan_k<<<512, 256, 0, stream>>>(dly, ucv, xz, xdbl, A_log, Dp);
  // 6. out_proj -> tmp (f32)           (N=1024,K=2048)
  gemm_bt<1><<<dim3(8,64), 256, 0, stream>>>(dly, 2048, wout, nullptr, tmp, MTOK, 1024, 2048);
  // 7. h = rmsnorm(tmp + x_f32) * norm_w -> hbuf (bf16)
  add_rms_k<false,true><<<MTOK, 256, 0, stream>>>(tmp, x_in, norm_w, hbuf);
  // 8. ffn1 + bias + gelu -> xz (reused) (N=4096,K=1024)
  cvt_k<<<2048, 256, 0, stream>>>(w_f1, wA, (4*DM*DM)/8);
  gemm_bt<3><<<dim3(32,64), 256, 0, stream>>>(hbuf, 1024, wA, b_f1, xz, MTOK, 4096, 1024);
  // 9. ffn2 + bias -> tmp (f32)          (N=1024,K=4096)
  cvt_k<<<2048, 256, 0, stream>>>(w_f2, wA, (4*DM*DM)/8);
  gemm_bt<4><<<dim3(8,64), 256, 0, stream>>>(xz, 4096, wA, b_f2, tmp, MTOK, 1024, 4096);
  // 10. out = rmsnorm(tmp + hbuf) * ffn_norm_w -> d_out (f32)
  add_rms_k<true,false><<<MTOK, 256, 0, stream>>>(tmp, hbuf, norm2, d_out);
}

// Round 3
// 1010.236 us; speedup vs baseline: 2.1853x; 2.1853x over previous
//
#include <hip/hip_runtime.h>
#include <cstdint>
#include <cstddef>

#define SEQ    2048
#define NB     4
#define DM     1024
#define DI     2048
#define MTOK   (NB*SEQ)   // 8192
#define TC     64         // scan time-chunk

typedef unsigned short u16;
typedef __attribute__((ext_vector_type(8))) short  short8;
typedef __attribute__((ext_vector_type(4))) float  f32x4;
typedef __attribute__((ext_vector_type(4))) unsigned short us4;

__device__ __forceinline__ float b2f(u16 u){ union{unsigned i; float f;} c; c.i=((unsigned)u)<<16; return c.f; }
__device__ __forceinline__ u16 f2b(float f){
  union{float f; unsigned u;} c; c.f=f;
  unsigned r = c.u + 0x7fffu + ((c.u>>16)&1u);
  return (u16)(r>>16);
}

__device__ __forceinline__ void gload_lds16(const void* g, void* l){
  __builtin_amdgcn_global_load_lds((const __attribute__((address_space(1))) void*)g,
                                   (__attribute__((address_space(3))) void*)l, 16, 0, 0);
}

// ---------------- f32 -> bf16 conversion (8 elements/thread) ----------------
__global__ __launch_bounds__(256) void cvt_k(const float* __restrict__ in,
                                             u16* __restrict__ out, int n8){
  const int i = blockIdx.x*256 + threadIdx.x;
  if (i >= n8) return;
  const f32x4 a = ((const f32x4*)in)[2*i];
  const f32x4 b = ((const f32x4*)in)[2*i+1];
  short8 r;
  #pragma unroll
  for (int e=0;e<4;e++){ r[e] = (short)f2b(a[e]); r[e+4] = (short)f2b(b[e]); }
  ((short8*)out)[i] = r;
}

// ---------------- x_proj_w (96,2048) f32 -> padded (128,2048) bf16 ----------------
__global__ __launch_bounds__(256) void padcvt_k(const float* __restrict__ in,
                                                u16* __restrict__ out){
  const int i = blockIdx.x*256 + threadIdx.x;   // 32768 threads, 8 elems each
  const int row = (i*8) >> 11;
  short8 r;
  if (row < 96){
    const f32x4 a = ((const f32x4*)in)[2*i];
    const f32x4 b = ((const f32x4*)in)[2*i+1];
    #pragma unroll
    for (int e=0;e<4;e++){ r[e] = (short)f2b(a[e]); r[e+4] = (short)f2b(b[e]); }
  } else {
    #pragma unroll
    for (int e=0;e<8;e++) r[e] = 0;
  }
  ((short8*)out)[i] = r;
}

// ---------------- generic NT GEMM: C[M,N] = X[M,K] * W[N,K]^T (bf16 in) ----------------
// EPI: 0 = store bf16; 1 = store f32; 2 = +bias,softplus -> bf16;
//      3 = +bias,gelu(exact) -> bf16; 4 = +bias -> f32
template<int EPI>
__global__ __launch_bounds__(256) void gemm_bt(
    const u16* __restrict__ X, int lda,
    const u16* __restrict__ W,
    const float* __restrict__ bias,
    void* __restrict__ Cout,
    int M, int N, int K)
{
  __shared__ __align__(16) u16 As[128*64];
  __shared__ __align__(16) u16 Bs[128*64];
  const int tid  = threadIdx.x;
  const int lane = tid & 63;
  const int wv   = tid >> 6;
  const int wr   = wv >> 1, wc = wv & 1;
  const int bm0  = blockIdx.y * 128;
  const int bn0  = blockIdx.x * 128;
  const int r0   = tid >> 3;          // 0..31
  const int c8   = (tid & 7) << 3;    // element offset 0..56

  f32x4 acc[4][4];
  #pragma unroll
  for (int i=0;i<4;i++)
    #pragma unroll
    for (int j=0;j<4;j++){ f32x4 z = {0.f,0.f,0.f,0.f}; acc[i][j] = z; }

  const int lrow = lane & 15;
  const int lko  = (lane >> 4) << 3;

  for (int kt = 0; kt < K; kt += 64) {
    #pragma unroll
    for (int c = 0; c < 4; ++c) {
      const int row = c*32 + r0;
      gload_lds16(X + (size_t)(bm0+row)*lda + kt + c8, &As[row*64 + c8]);
      gload_lds16(W + (size_t)(bn0+row)*K   + kt + c8, &Bs[row*64 + c8]);
    }
    __syncthreads();
    #pragma unroll
    for (int kk = 0; kk < 2; ++kk) {
      short8 af[4], bf[4];
      #pragma unroll
      for (int i=0;i<4;i++) af[i] = *(const short8*)&As[(wr*64 + i*16 + lrow)*64 + kk*32 + lko];
      #pragma unroll
      for (int j=0;j<4;j++) bf[j] = *(const short8*)&Bs[(wc*64 + j*16 + lrow)*64 + kk*32 + lko];
      #pragma unroll
      for (int i=0;i<4;i++)
        #pragma unroll
        for (int j=0;j<4;j++)
          acc[i][j] = __builtin_amdgcn_mfma_f32_16x16x32_bf16(af[i], bf[j], acc[i][j], 0, 0, 0);
    }
    __syncthreads();
  }

  const int rbase = bm0 + wr*64 + ((lane>>4)<<2);
  const int cbase = bn0 + wc*64 + (lane & 15);
  #pragma unroll
  for (int i=0;i<4;i++) {
    #pragma unroll
    for (int j=0;j<4;j++) {
      const int col = cbase + j*16;
      float bval = 0.f;
      if constexpr (EPI >= 2) bval = bias[col];
      #pragma unroll
      for (int r=0;r<4;r++) {
        const int row = rbase + i*16 + r;
        const float v = acc[i][j][r];
        const size_t oid = (size_t)row*N + col;
        if constexpr (EPI == 0) {
          ((u16*)Cout)[oid] = f2b(v);
        } else if constexpr (EPI == 1) {
          ((float*)Cout)[oid] = v;
        } else if constexpr (EPI == 2) {
          float xv = v + bval;
          float sp = (xv > 20.f) ? xv : log1pf(__expf(xv));
          ((u16*)Cout)[oid] = f2b(sp);
        } else if constexpr (EPI == 3) {
          float xv = v + bval;
          float g = 0.5f*xv*(1.f + erff(xv*0.70710678118f));
          ((u16*)Cout)[oid] = f2b(g);
        } else {
          ((float*)Cout)[oid] = v + bval;
        }
      }
    }
  }
}

// ---------------- causal depthwise conv (width 4) + SiLU ----------------
__global__ __launch_bounds__(256) void conv_silu_k(
    const u16* __restrict__ xz, const float* __restrict__ cw,
    const float* __restrict__ cb, u16* __restrict__ uout)
{
  const int m  = blockIdx.x;          // token index
  const int t  = m & (SEQ-1);
  const int d8 = threadIdx.x << 3;    // 8 channels per thread
  float w[4][8];                      // [tap][chan]
  const float* wp = cw + (size_t)d8*4;
  #pragma unroll
  for (int q=0;q<8;q++){
    f32x4 v = ((const f32x4*)wp)[q];
    #pragma unroll
    for (int e=0;e<4;e++){ int li=q*4+e; w[li&3][li>>2]=v[e]; }
  }
  float acc[8];
  {
    f32x4 b0 = ((const f32x4*)&cb[d8])[0];
    f32x4 b1 = ((const f32x4*)&cb[d8])[1];
    #pragma unroll
    for (int e=0;e<4;e++){ acc[e]=b0[e]; acc[e+4]=b1[e]; }
  }
  #pragma unroll
  for (int j=0;j<4;j++){
    const int tt = t - 3 + j;
    if (tt >= 0){
      short8 v = *(const short8*)&xz[(size_t)(m-3+j)*4096 + d8];
      #pragma unroll
      for (int e=0;e<8;e++) acc[e] = fmaf(b2f((u16)v[e]), w[j][e], acc[e]);
    }
  }
  short8 r;
  #pragma unroll
  for (int e=0;e<8;e++){
    float x = acc[e];
    r[e] = (short)f2b(x / (1.f + __expf(-x)));
  }
  *(short8*)&uout[(size_t)m*2048 + d8] = r;
}

// ---------------- selective scan: LDS-staged chunks, fused +u*D and *silu(z) ---------
// grid: 512 blocks of 256. block -> (b = blk>>7, d0 = (blk&127)*16).
// thread: n = tid&15 (state), d_loc = tid>>4 (channel within 16-block).
// dly holds delta (bf16) on input, gated y (bf16) on output (in place).
__global__ __launch_bounds__(256) void scan_k(
    u16* __restrict__ dly,
    const u16* __restrict__ ucv,
    const u16* __restrict__ xz,
    const u16* __restrict__ xdbl,
    const float* __restrict__ A_log,
    const float* __restrict__ Dp)
{
  __shared__ float sDel[TC][16];
  __shared__ float sDU [TC][16];
  __shared__ __align__(16) u16 sBC[TC][32];
  __shared__ float sY  [TC][16];

  const int tid   = threadIdx.x;
  const int b     = blockIdx.x >> 7;
  const int d0    = (blockIdx.x & 127) << 4;
  const int n     = tid & 15;
  const int d_loc = tid >> 4;           // 0..15
  const float A   = -__expf(A_log[(d0 + d_loc)*16 + n]);

  // staging/store-phase mapping: 4 threads per t-row
  const int st_t = tid >> 2;            // 0..63
  const int st_q = (tid & 3) << 2;      // 0,4,8,12 (elements)
  const int bc_q = (tid & 3) << 3;      // 0,8,16,24 (elements)
  const f32x4 Dv = *(const f32x4*)&Dp[d0 + st_q];

  const size_t rowD = (size_t)(b*SEQ)*DI   + d0;   // dly/ucv base (+t*DI)
  const size_t rowX = (size_t)(b*SEQ)*128  + 64;   // xdbl B/C base (+t*128)
  const size_t rowZ = (size_t)(b*SEQ)*4096 + DI + d0; // z base (+t*4096)

  float h = 0.f;

  // prefetch chunk 0 into registers
  us4    rD  = *(const us4*)   &dly [rowD + (size_t)st_t*DI  + st_q];
  us4    rU  = *(const us4*)   &ucv [rowD + (size_t)st_t*DI  + st_q];
  short8 rBC = *(const short8*)&xdbl[rowX + (size_t)st_t*128 + bc_q];

  for (int tc = 0; tc < SEQ; tc += TC) {
    __syncthreads();                    // LDS consumers of previous chunk done
    {
      f32x4 del, du;
      #pragma unroll
      for (int e=0;e<4;e++){ del[e] = b2f(rD[e]); du[e] = del[e]*b2f(rU[e]); }
      *(f32x4*)&sDel[st_t][st_q] = del;
      *(f32x4*)&sDU [st_t][st_q] = du;
      *(short8*)&sBC[st_t][bc_q] = rBC;
    }
    if (tc + TC < SEQ) {                // issue next chunk's loads early
      const size_t tn = (size_t)(tc + TC + st_t);
      rD  = *(const us4*)   &dly [rowD + tn*DI  + st_q];
      rU  = *(const us4*)   &ucv [rowD + tn*DI  + st_q];
      rBC = *(const short8*)&xdbl[rowX + tn*128 + bc_q];
    }
    __syncthreads();

    #pragma unroll 4
    for (int t = 0; t < TC; ++t) {
      const float del = sDel[t][d_loc];
      const float du  = sDU [t][d_loc];
      const float Bv  = b2f(sBC[t][n]);
      const float Cv  = b2f(sBC[t][16+n]);
      const float dA  = __expf(del * A);
      h = fmaf(dA, h, du * Bv);
      float p = h * Cv;
      p += __shfl_xor(p, 1);
      p += __shfl_xor(p, 2);
      p += __shfl_xor(p, 4);
      p += __shfl_xor(p, 8);
      if (n == 0) sY[t][d_loc] = p;
    }
    __syncthreads();                    // sY complete

    {   // store phase: y = (p + u*D) * silu(z), coalesced
      const size_t tg = (size_t)(tc + st_t);
      const f32x4 p4 = *(const f32x4*)&sY[st_t][st_q];
      const us4 zu = *(const us4*)&xz [rowZ + tg*4096 + st_q];
      const us4 uu = *(const us4*)&ucv[rowD + tg*DI   + st_q];
      us4 outv;
      #pragma unroll
      for (int e=0;e<4;e++){
        float y = fmaf(b2f(uu[e]), Dv[e], p4[e]);
        const float z = b2f(zu[e]);
        y *= z / (1.f + __expf(-z));
        outv[e] = (unsigned short)f2b(y);
      }
      *(us4*)&dly[rowD + tg*DI + st_q] = outv;
    }
  }
}

// ---------------- out = rmsnorm(a_f32 + res) * w  (row=1024) ----------------
template<bool RES_BF, bool OUT_BF>
__global__ __launch_bounds__(256) void add_rms_k(
    const float* __restrict__ a, const void* __restrict__ res,
    const float* __restrict__ wgt, void* __restrict__ out)
{
  const int row = blockIdx.x;
  const int tid = threadIdx.x;
  const size_t base = (size_t)row*DM + tid*4;
  const f32x4 av = *(const f32x4*)&a[base];
  const f32x4 wv = *(const f32x4*)&wgt[tid*4];
  float v[4]; float ss = 0.f;
  if constexpr (RES_BF) {
    const us4 rv = *(const us4*)&((const u16*)res)[base];
    #pragma unroll
    for (int j=0;j<4;j++){ v[j] = av[j] + b2f(rv[j]); ss = fmaf(v[j], v[j], ss); }
  } else {
    const f32x4 rv = *(const f32x4*)&((const float*)res)[base];
    #pragma unroll
    for (int j=0;j<4;j++){ v[j] = av[j] + rv[j]; ss = fmaf(v[j], v[j], ss); }
  }
  #pragma unroll
  for (int off=32; off>=1; off>>=1) ss += __shfl_xor(ss, off);
  __shared__ float sred[4];
  if ((tid & 63) == 0) sred[tid>>6] = ss;
  __syncthreads();
  const float tot = sred[0]+sred[1]+sred[2]+sred[3];
  const float rs = rsqrtf(tot * (1.f/1024.f) + 1e-12f);
  if constexpr (OUT_BF) {
    us4 ov;
    #pragma unroll
    for (int j=0;j<4;j++) ov[j] = (unsigned short)f2b(v[j] * rs * wv[j]);
    *(us4*)&((u16*)out)[base] = ov;
  } else {
    f32x4 ov;
    #pragma unroll
    for (int j=0;j<4;j++) ov[j] = v[j] * rs * wv[j];
    *(f32x4*)&((float*)out)[base] = ov;
  }
}

extern "C" void kernel_launch(void* const* d_in, const int* in_sizes, int n_in,
                              void* d_out, int out_size, void* d_ws, size_t ws_size,
                              hipStream_t stream) {
  (void)in_sizes; (void)n_in; (void)out_size; (void)ws_size;
  const float* x_in  = (const float*)d_in[0];
  const float* w_inp = (const float*)d_in[1];
  const float* conv_w= (const float*)d_in[2];
  const float* conv_b= (const float*)d_in[3];
  const float* w_xp  = (const float*)d_in[4];
  const float* w_dt  = (const float*)d_in[5];
  const float* b_dt  = (const float*)d_in[6];
  const float* A_log = (const float*)d_in[7];
  const float* Dp    = (const float*)d_in[8];
  const float* w_out = (const float*)d_in[9];
  const float* norm_w= (const float*)d_in[10];
  const float* w_f1  = (const float*)d_in[11];
  const float* b_f1  = (const float*)d_in[12];
  const float* w_f2  = (const float*)d_in[13];
  const float* b_f2  = (const float*)d_in[14];
  const float* norm2 = (const float*)d_in[15];

  char* ws = (char*)d_ws;
  size_t off = 0;
  auto alloc = [&](size_t bytes){ void* p = ws + off; off += (bytes + 255) & ~255ull; return p; };
  u16*   xz   = (u16*)  alloc((size_t)MTOK*4096*2);  // xz, later ffn hidden
  u16*   ucv  = (u16*)  alloc((size_t)MTOK*2048*2);  // later aliased by hbuf
  u16*   xdbl = (u16*)  alloc((size_t)MTOK*128*2);
  u16*   dly  = (u16*)  alloc((size_t)MTOK*2048*2);  // delta, then ygated in place
  float* tmp  = (float*)alloc((size_t)MTOK*1024*4);
  u16*   wA   = (u16*)  alloc((size_t)4096*1024*2);  // reused weight slot
  u16*   wpad = (u16*)  alloc((size_t)128*2048*2);
  u16*   wdt  = (u16*)  alloc((size_t)2048*64*2);
  u16*   wout = (u16*)  alloc((size_t)1024*2048*2);
  u16*   xbf  = (u16*)tmp;   // x bf16, dead before tmp is written
  u16*   hbuf = ucv;         // h bf16, born after ucv's last read

  // --- convert f32 operands feeding MFMA to bf16 ---
  cvt_k<<<4096, 256, 0, stream>>>(x_in,  xbf, MTOK*DM/8);
  cvt_k<<<2048, 256, 0, stream>>>(w_inp, wA,  (2*DI*DM)/8);
  padcvt_k<<<128, 256, 0, stream>>>(w_xp, wpad);
  cvt_k<<<64,   256, 0, stream>>>(w_dt,  wdt, (DI*64)/8);
  cvt_k<<<1024, 256, 0, stream>>>(w_out, wout,(DM*DI)/8);

  // 1. in_proj: xz = x @ in_proj_w^T   (M=8192,N=4096,K=1024)
  gemm_bt<0><<<dim3(32,64), 256, 0, stream>>>(xbf, 1024, wA, nullptr, xz, MTOK, 4096, 1024);
  // 2. causal dwconv + silu -> ucv
  conv_silu_k<<<MTOK, 256, 0, stream>>>(xz, conv_w, conv_b, ucv);
  // 3. x_proj: xdbl = ucv @ wpad^T     (N=128,K=2048)
  gemm_bt<0><<<dim3(1,64), 256, 0, stream>>>(ucv, 2048, wpad, nullptr, xdbl, MTOK, 128, 2048);
  // 4. dt_proj + softplus -> delta     (N=2048,K=64; X = xdbl[:, :64], lda=128)
  gemm_bt<2><<<dim3(16,64), 256, 0, stream>>>(xdbl, 128, wdt, b_dt, dly, MTOK, 2048, 64);
  // 5. selective scan (fused +u*D, *silu(z)) -> ygated in dly
  scan_k<<<512, 256, 0, stream>>>(dly, ucv, xz, xdbl, A_log, Dp);
  // 6. out_proj -> tmp (f32)           (N=1024,K=2048)
  gemm_bt<1><<<dim3(8,64), 256, 0, stream>>>(dly, 2048, wout, nullptr, tmp, MTOK, 1024, 2048);
  // 7. h = rmsnorm(tmp + x_f32) * norm_w -> hbuf (bf16)
  add_rms_k<false,true><<<MTOK, 256, 0, stream>>>(tmp, x_in, norm_w, hbuf);
  // 8. ffn1 + bias + gelu -> xz (reused) (N=4096,K=1024)
  cvt_k<<<2048, 256, 0, stream>>>(w_f1, wA, (4*DM*DM)/8);
  gemm_bt<3><<<dim3(32,64), 256, 0, stream>>>(hbuf, 1024, wA, b_f1, xz, MTOK, 4096, 1024);
  // 9. ffn2 + bias -> tmp (f32)          (N=1024,K=4096)
  cvt_k<<<2048, 256, 0, stream>>>(w_f2, wA, (4*DM*DM)/8);
  gemm_bt<4><<<dim3(8,64), 256, 0, stream>>>(xz, 4096, wA, b_f2, tmp, MTOK, 1024, 4096);
  // 10. out = rmsnorm(tmp + hbuf) * ffn_norm_w -> d_out (f32)
  add_rms_k<true,false><<<MTOK, 256, 0, stream>>>(tmp, hbuf, norm2, d_out);
}

// Round 4
// 728.995 us; speedup vs baseline: 3.0284x; 1.3858x over previous
//
#include <hip/hip_runtime.h>
#include <cstdint>
#include <cstddef>

#define SEQ    2048
#define NB     4
#define DM     1024
#define DI     2048
#define MTOK   (NB*SEQ)   // 8192
#define NCHUNK 16
#define TCH    128        // steps per chunk

typedef unsigned short u16;
typedef __attribute__((ext_vector_type(8))) short  short8;
typedef __attribute__((ext_vector_type(4))) float  f32x4;
typedef __attribute__((ext_vector_type(4))) unsigned short us4;

__device__ __forceinline__ float b2f(u16 u){ union{unsigned i; float f;} c; c.i=((unsigned)u)<<16; return c.f; }
__device__ __forceinline__ u16 f2b(float f){
  union{float f; unsigned u;} c; c.f=f;
  unsigned r = c.u + 0x7fffu + ((c.u>>16)&1u);
  return (u16)(r>>16);
}

__device__ __forceinline__ void gload_lds16(const void* g, void* l){
  __builtin_amdgcn_global_load_lds((const __attribute__((address_space(1))) void*)g,
                                   (__attribute__((address_space(3))) void*)l, 16, 0, 0);
}

// ---------------- f32 -> bf16 conversion (8 elements/thread) ----------------
__global__ __launch_bounds__(256) void cvt_k(const float* __restrict__ in,
                                             u16* __restrict__ out, int n8){
  const int i = blockIdx.x*256 + threadIdx.x;
  if (i >= n8) return;
  const f32x4 a = ((const f32x4*)in)[2*i];
  const f32x4 b = ((const f32x4*)in)[2*i+1];
  short8 r;
  #pragma unroll
  for (int e=0;e<4;e++){ r[e] = (short)f2b(a[e]); r[e+4] = (short)f2b(b[e]); }
  ((short8*)out)[i] = r;
}

// ---------------- x_proj_w (96,2048) f32 -> padded (128,2048) bf16 ----------------
__global__ __launch_bounds__(256) void padcvt_k(const float* __restrict__ in,
                                                u16* __restrict__ out){
  const int i = blockIdx.x*256 + threadIdx.x;   // 32768 threads, 8 elems each
  const int row = (i*8) >> 11;
  short8 r;
  if (row < 96){
    const f32x4 a = ((const f32x4*)in)[2*i];
    const f32x4 b = ((const f32x4*)in)[2*i+1];
    #pragma unroll
    for (int e=0;e<4;e++){ r[e] = (short)f2b(a[e]); r[e+4] = (short)f2b(b[e]); }
  } else {
    #pragma unroll
    for (int e=0;e<8;e++) r[e] = 0;
  }
  ((short8*)out)[i] = r;
}

// ---------------- generic NT GEMM: C[M,N] = X[M,K] * W[N,K]^T (bf16 in) ----------------
// EPI: 0 = store bf16; 1 = store f32; 2 = +bias,softplus -> bf16;
//      3 = +bias,gelu(exact) -> bf16; 4 = +bias -> f32
template<int EPI>
__global__ __launch_bounds__(256) void gemm_bt(
    const u16* __restrict__ X, int lda,
    const u16* __restrict__ W,
    const float* __restrict__ bias,
    void* __restrict__ Cout,
    int M, int N, int K)
{
  __shared__ __align__(16) u16 As[128*64];
  __shared__ __align__(16) u16 Bs[128*64];
  const int tid  = threadIdx.x;
  const int lane = tid & 63;
  const int wv   = tid >> 6;
  const int wr   = wv >> 1, wc = wv & 1;
  const int bm0  = blockIdx.y * 128;
  const int bn0  = blockIdx.x * 128;
  const int r0   = tid >> 3;          // 0..31
  const int c8   = (tid & 7) << 3;    // element offset 0..56

  f32x4 acc[4][4];
  #pragma unroll
  for (int i=0;i<4;i++)
    #pragma unroll
    for (int j=0;j<4;j++){ f32x4 z = {0.f,0.f,0.f,0.f}; acc[i][j] = z; }

  const int lrow = lane & 15;
  const int lko  = (lane >> 4) << 3;

  for (int kt = 0; kt < K; kt += 64) {
    #pragma unroll
    for (int c = 0; c < 4; ++c) {
      const int row = c*32 + r0;
      gload_lds16(X + (size_t)(bm0+row)*lda + kt + c8, &As[row*64 + c8]);
      gload_lds16(W + (size_t)(bn0+row)*K   + kt + c8, &Bs[row*64 + c8]);
    }
    __syncthreads();
    #pragma unroll
    for (int kk = 0; kk < 2; ++kk) {
      short8 af[4], bf[4];
      #pragma unroll
      for (int i=0;i<4;i++) af[i] = *(const short8*)&As[(wr*64 + i*16 + lrow)*64 + kk*32 + lko];
      #pragma unroll
      for (int j=0;j<4;j++) bf[j] = *(const short8*)&Bs[(wc*64 + j*16 + lrow)*64 + kk*32 + lko];
      #pragma unroll
      for (int i=0;i<4;i++)
        #pragma unroll
        for (int j=0;j<4;j++)
          acc[i][j] = __builtin_amdgcn_mfma_f32_16x16x32_bf16(af[i], bf[j], acc[i][j], 0, 0, 0);
    }
    __syncthreads();
  }

  const int rbase = bm0 + wr*64 + ((lane>>4)<<2);
  const int cbase = bn0 + wc*64 + (lane & 15);
  #pragma unroll
  for (int i=0;i<4;i++) {
    #pragma unroll
    for (int j=0;j<4;j++) {
      const int col = cbase + j*16;
      float bval = 0.f;
      if constexpr (EPI >= 2) bval = bias[col];
      #pragma unroll
      for (int r=0;r<4;r++) {
        const int row = rbase + i*16 + r;
        const float v = acc[i][j][r];
        const size_t oid = (size_t)row*N + col;
        if constexpr (EPI == 0) {
          ((u16*)Cout)[oid] = f2b(v);
        } else if constexpr (EPI == 1) {
          ((float*)Cout)[oid] = v;
        } else if constexpr (EPI == 2) {
          float xv = v + bval;
          float sp = (xv > 20.f) ? xv : log1pf(__expf(xv));
          ((u16*)Cout)[oid] = f2b(sp);
        } else if constexpr (EPI == 3) {
          float xv = v + bval;
          float g = 0.5f*xv*(1.f + erff(xv*0.70710678118f));
          ((u16*)Cout)[oid] = f2b(g);
        } else {
          ((float*)Cout)[oid] = v + bval;
        }
      }
    }
  }
}

// ---------------- causal depthwise conv (width 4) + SiLU ----------------
__global__ __launch_bounds__(256) void conv_silu_k(
    const u16* __restrict__ xz, const float* __restrict__ cw,
    const float* __restrict__ cb, u16* __restrict__ uout)
{
  const int m  = blockIdx.x;          // token index
  const int t  = m & (SEQ-1);
  const int d8 = threadIdx.x << 3;    // 8 channels per thread
  float w[4][8];                      // [tap][chan]
  const float* wp = cw + (size_t)d8*4;
  #pragma unroll
  for (int q=0;q<8;q++){
    f32x4 v = ((const f32x4*)wp)[q];
    #pragma unroll
    for (int e=0;e<4;e++){ int li=q*4+e; w[li&3][li>>2]=v[e]; }
  }
  float acc[8];
  {
    f32x4 b0 = ((const f32x4*)&cb[d8])[0];
    f32x4 b1 = ((const f32x4*)&cb[d8])[1];
    #pragma unroll
    for (int e=0;e<4;e++){ acc[e]=b0[e]; acc[e+4]=b1[e]; }
  }
  #pragma unroll
  for (int j=0;j<4;j++){
    const int tt = t - 3 + j;
    if (tt >= 0){
      short8 v = *(const short8*)&xz[(size_t)(m-3+j)*4096 + d8];
      #pragma unroll
      for (int e=0;e<8;e++) acc[e] = fmaf(b2f((u16)v[e]), w[j][e], acc[e]);
    }
  }
  short8 r;
  #pragma unroll
  for (int e=0;e<8;e++){
    float x = acc[e];
    r[e] = (short)f2b(x / (1.f + __expf(-x)));
  }
  *(short8*)&uout[(size_t)m*2048 + d8] = r;
}

// ================= chunked selective scan: 1 thread = 1 channel, h[16] in regs ========
// grid: (32 chgrp, NCHUNK). block=256 threads, thread ch = chgrp*256+tid.
// PASS 1: h=0, compute chunk summary hfin[16] + S=sum(delta)  (decay = exp(A*S)).
// PASS 3: h=hinit from summ, emit y = (sum_n h*C + u*D)*silu(z) into dly (in place).
// summ layout: summ[(chunk*17 + n)*8192 + ch], n=16 slot holds S.
template<int PASS>
__global__ __launch_bounds__(256) void scan_chunk_k(
    u16* __restrict__ dly,
    const u16* __restrict__ ucv,
    const u16* __restrict__ xz,
    const u16* __restrict__ xdbl,
    const float* __restrict__ A_log,
    const float* __restrict__ Dp,
    float* __restrict__ summ)
{
  __shared__ __align__(16) u16 sBC [TCH*32];   // B|C per step, 8KB
  __shared__ __align__(16) u16 sDel[16*256];
  __shared__ __align__(16) u16 sU  [16*256];
  __shared__ __align__(16) u16 sZ  [16*256];

  const int tid   = threadIdx.x;
  const int chgrp = blockIdx.x;        // 0..31
  const int chunk = blockIdx.y;
  const int ch    = chgrp*256 + tid;
  const int b     = ch >> 11;
  const int d     = ch & (DI-1);
  const int t0    = chunk*TCH;
  const int dbase = (chgrp & 7) << 8;

  float A[16];
  #pragma unroll
  for (int n=0;n<16;n++) A[n] = -__expf(A_log[d*16 + n]);

  // stage B/C for the whole chunk (rows t0..t0+127, 32 u16 each)
  #pragma unroll
  for (int k=0;k<2;k++){
    const int i = k*256 + tid;
    const int row = i >> 2, q8 = (i & 3) << 3;
    *(short8*)&sBC[row*32 + q8] =
      *(const short8*)&xdbl[((size_t)(b*SEQ) + t0 + row)*128 + 64 + q8];
  }

  float h[16];
  if constexpr (PASS == 1) {
    #pragma unroll
    for (int n=0;n<16;n++) h[n] = 0.f;
  } else {
    #pragma unroll
    for (int n=0;n<16;n++) h[n] = summ[((size_t)(chunk*17 + n))*8192 + ch];
  }
  float S = 0.f;
  float Dd = 0.f;
  if constexpr (PASS == 3) Dd = Dp[d];

  const int srow = tid >> 5;            // 0..7
  const int scol = (tid & 31) << 3;
  const size_t gD = (size_t)(b*SEQ)*DI   + dbase + scol;
  const size_t gZ = (size_t)(b*SEQ)*4096 + 2048 + dbase + scol;

  short8 pD[2], pU[2], pZ[2];
  #pragma unroll
  for (int k=0;k<2;k++){
    const size_t tg = (size_t)(t0 + k*8 + srow);
    pD[k] = *(const short8*)&dly[gD + tg*DI];
    pU[k] = *(const short8*)&ucv[gD + tg*DI];
    if constexpr (PASS == 3) pZ[k] = *(const short8*)&xz[gZ + tg*4096];
  }

  for (int sc = 0; sc < 8; ++sc) {
    __syncthreads();
    #pragma unroll
    for (int k=0;k<2;k++){
      *(short8*)&sDel[(k*8+srow)*256 + scol] = pD[k];
      *(short8*)&sU  [(k*8+srow)*256 + scol] = pU[k];
      if constexpr (PASS == 3) *(short8*)&sZ[(k*8+srow)*256 + scol] = pZ[k];
    }
    if (sc < 7) {   // prefetch next tile; stays in flight under this tile's compute
      #pragma unroll
      for (int k=0;k<2;k++){
        const size_t tg = (size_t)(t0 + (sc+1)*16 + k*8 + srow);
        pD[k] = *(const short8*)&dly[gD + tg*DI];
        pU[k] = *(const short8*)&ucv[gD + tg*DI];
        if constexpr (PASS == 3) pZ[k] = *(const short8*)&xz[gZ + tg*4096];
      }
    }
    __syncthreads();

    #pragma unroll 2
    for (int j=0; j<16; ++j){
      const int r = sc*16 + j;
      const float del = b2f(sDel[j*256 + tid]);
      const float u   = b2f(sU  [j*256 + tid]);
      const float du  = del * u;
      if constexpr (PASS == 1) S += del;
      const short8 bv0 = *(const short8*)&sBC[r*32];
      const short8 bv1 = *(const short8*)&sBC[r*32 + 8];
      short8 cv0, cv1;
      if constexpr (PASS == 3){
        cv0 = *(const short8*)&sBC[r*32 + 16];
        cv1 = *(const short8*)&sBC[r*32 + 24];
      }
      float p0=0.f, p1=0.f, p2=0.f, p3=0.f;
      #pragma unroll
      for (int n=0;n<16;++n){
        const float Bn = b2f((u16)(n<8 ? bv0[n] : bv1[n-8]));
        const float eA = __expf(del * A[n]);
        h[n] = fmaf(eA, h[n], du * Bn);
        if constexpr (PASS == 3){
          const float Cn = b2f((u16)(n<8 ? cv0[n] : cv1[n-8]));
          if      ((n&3)==0) p0 = fmaf(h[n], Cn, p0);
          else if ((n&3)==1) p1 = fmaf(h[n], Cn, p1);
          else if ((n&3)==2) p2 = fmaf(h[n], Cn, p2);
          else               p3 = fmaf(h[n], Cn, p3);
        }
      }
      if constexpr (PASS == 3){
        const float p = (p0+p1)+(p2+p3);
        const float z = b2f(sZ[j*256 + tid]);
        float y = fmaf(u, Dd, p);
        y *= z / (1.f + __expf(-z));
        dly[(size_t)(b*SEQ + t0 + r)*DI + d] = f2b(y);
      }
    }
  }

  if constexpr (PASS == 1){
    #pragma unroll
    for (int n=0;n<16;n++) summ[((size_t)(chunk*17 + n))*8192 + ch] = h[n];
    summ[((size_t)(chunk*17 + 16))*8192 + ch] = S;
  }
}

// combine chunk summaries -> per-chunk initial states (in place over summ)
__global__ __launch_bounds__(256) void scan_combine_k(
    float* __restrict__ summ, const float* __restrict__ A_log)
{
  const int ch = blockIdx.x*256 + threadIdx.x;   // 0..8191
  const int d  = ch & (DI-1);
  float A[16];
  #pragma unroll
  for (int n=0;n<16;n++) A[n] = -__expf(A_log[d*16 + n]);
  float hi[16];
  #pragma unroll
  for (int n=0;n<16;n++) hi[n] = 0.f;
  for (int c=0; c<NCHUNK; ++c){
    float hf[16]; float Sc = 0.f;
    if (c < NCHUNK-1) {
      #pragma unroll
      for (int n=0;n<16;n++) hf[n] = summ[((size_t)(c*17 + n))*8192 + ch];
      Sc = summ[((size_t)(c*17 + 16))*8192 + ch];
    }
    #pragma unroll
    for (int n=0;n<16;n++) summ[((size_t)(c*17 + n))*8192 + ch] = hi[n];
    if (c < NCHUNK-1) {
      #pragma unroll
      for (int n=0;n<16;n++) hi[n] = fmaf(__expf(A[n]*Sc), hi[n], hf[n]);
    }
  }
}

// ---------------- out = rmsnorm(a_f32 + res) * w  (row=1024) ----------------
template<bool RES_BF, bool OUT_BF>
__global__ __launch_bounds__(256) void add_rms_k(
    const float* __restrict__ a, const void* __restrict__ res,
    const float* __restrict__ wgt, void* __restrict__ out)
{
  const int row = blockIdx.x;
  const int tid = threadIdx.x;
  const size_t base = (size_t)row*DM + tid*4;
  const f32x4 av = *(const f32x4*)&a[base];
  const f32x4 wv = *(const f32x4*)&wgt[tid*4];
  float v[4]; float ss = 0.f;
  if constexpr (RES_BF) {
    const us4 rv = *(const us4*)&((const u16*)res)[base];
    #pragma unroll
    for (int j=0;j<4;j++){ v[j] = av[j] + b2f(rv[j]); ss = fmaf(v[j], v[j], ss); }
  } else {
    const f32x4 rv = *(const f32x4*)&((const float*)res)[base];
    #pragma unroll
    for (int j=0;j<4;j++){ v[j] = av[j] + rv[j]; ss = fmaf(v[j], v[j], ss); }
  }
  #pragma unroll
  for (int off=32; off>=1; off>>=1) ss += __shfl_xor(ss, off);
  __shared__ float sred[4];
  if ((tid & 63) == 0) sred[tid>>6] = ss;
  __syncthreads();
  const float tot = sred[0]+sred[1]+sred[2]+sred[3];
  const float rs = rsqrtf(tot * (1.f/1024.f) + 1e-12f);
  if constexpr (OUT_BF) {
    us4 ov;
    #pragma unroll
    for (int j=0;j<4;j++) ov[j] = (unsigned short)f2b(v[j] * rs * wv[j]);
    *(us4*)&((u16*)out)[base] = ov;
  } else {
    f32x4 ov;
    #pragma unroll
    for (int j=0;j<4;j++) ov[j] = v[j] * rs * wv[j];
    *(f32x4*)&((float*)out)[base] = ov;
  }
}

extern "C" void kernel_launch(void* const* d_in, const int* in_sizes, int n_in,
                              void* d_out, int out_size, void* d_ws, size_t ws_size,
                              hipStream_t stream) {
  (void)in_sizes; (void)n_in; (void)out_size; (void)ws_size;
  const float* x_in  = (const float*)d_in[0];
  const float* w_inp = (const float*)d_in[1];
  const float* conv_w= (const float*)d_in[2];
  const float* conv_b= (const float*)d_in[3];
  const float* w_xp  = (const float*)d_in[4];
  const float* w_dt  = (const float*)d_in[5];
  const float* b_dt  = (const float*)d_in[6];
  const float* A_log = (const float*)d_in[7];
  const float* Dp    = (const float*)d_in[8];
  const float* w_out = (const float*)d_in[9];
  const float* norm_w= (const float*)d_in[10];
  const float* w_f1  = (const float*)d_in[11];
  const float* b_f1  = (const float*)d_in[12];
  const float* w_f2  = (const float*)d_in[13];
  const float* b_f2  = (const float*)d_in[14];
  const float* norm2 = (const float*)d_in[15];

  char* ws = (char*)d_ws;
  size_t off = 0;
  auto alloc = [&](size_t bytes){ void* p = ws + off; off += (bytes + 255) & ~255ull; return p; };
  u16*   xz   = (u16*)  alloc((size_t)MTOK*4096*2);  // xz, later ffn hidden
  u16*   ucv  = (u16*)  alloc((size_t)MTOK*2048*2);  // later aliased by hbuf
  u16*   xdbl = (u16*)  alloc((size_t)MTOK*128*2);
  u16*   dly  = (u16*)  alloc((size_t)MTOK*2048*2);  // delta, then ygated in place
  float* tmp  = (float*)alloc((size_t)MTOK*1024*4);
  u16*   wA   = (u16*)  alloc((size_t)4096*1024*2);  // reused weight slot
  u16*   wpad = (u16*)  alloc((size_t)128*2048*2);
  u16*   wdt  = (u16*)  alloc((size_t)2048*64*2);
  u16*   wout = (u16*)  alloc((size_t)1024*2048*2);
  u16*   xbf  = (u16*)tmp;                 // lower half of tmp; dead after step 1
  float* summ = tmp + (size_t)MTOK*512;    // upper half of tmp; dead before step 6
  u16*   hbuf = ucv;                       // h bf16, born after ucv's last read

  // --- convert f32 operands feeding MFMA to bf16 ---
  cvt_k<<<4096, 256, 0, stream>>>(x_in,  xbf, MTOK*DM/8);
  cvt_k<<<2048, 256, 0, stream>>>(w_inp, wA,  (2*DI*DM)/8);
  padcvt_k<<<128, 256, 0, stream>>>(w_xp, wpad);
  cvt_k<<<64,   256, 0, stream>>>(w_dt,  wdt, (DI*64)/8);
  cvt_k<<<1024, 256, 0, stream>>>(w_out, wout,(DM*DI)/8);

  // 1. in_proj: xz = x @ in_proj_w^T   (M=8192,N=4096,K=1024)
  gemm_bt<0><<<dim3(32,64), 256, 0, stream>>>(xbf, 1024, wA, nullptr, xz, MTOK, 4096, 1024);
  // 2. causal dwconv + silu -> ucv
  conv_silu_k<<<MTOK, 256, 0, stream>>>(xz, conv_w, conv_b, ucv);
  // 3. x_proj: xdbl = ucv @ wpad^T     (N=128,K=2048)
  gemm_bt<0><<<dim3(1,64), 256, 0, stream>>>(ucv, 2048, wpad, nullptr, xdbl, MTOK, 128, 2048);
  // 4. dt_proj + softplus -> delta     (N=2048,K=64; X = xdbl[:, :64], lda=128)
  gemm_bt<2><<<dim3(16,64), 256, 0, stream>>>(xdbl, 128, wdt, b_dt, dly, MTOK, 2048, 64);
  // 5. selective scan: pass1 (summaries) -> combine -> pass3 (emit gated y in dly)
  scan_chunk_k<1><<<dim3(32, NCHUNK-1), 256, 0, stream>>>(dly, ucv, xz, xdbl, A_log, Dp, summ);
  scan_combine_k<<<32, 256, 0, stream>>>(summ, A_log);
  scan_chunk_k<3><<<dim3(32, NCHUNK), 256, 0, stream>>>(dly, ucv, xz, xdbl, A_log, Dp, summ);
  // 6. out_proj -> tmp (f32)           (N=1024,K=2048)
  gemm_bt<1><<<dim3(8,64), 256, 0, stream>>>(dly, 2048, wout, nullptr, tmp, MTOK, 1024, 2048);
  // 7. h = rmsnorm(tmp + x_f32) * norm_w -> hbuf (bf16)
  add_rms_k<false,true><<<MTOK, 256, 0, stream>>>(tmp, x_in, norm_w, hbuf);
  // 8. ffn1 + bias + gelu -> xz (reused) (N=4096,K=1024)
  cvt_k<<<2048, 256, 0, stream>>>(w_f1, wA, (4*DM*DM)/8);
  gemm_bt<3><<<dim3(32,64), 256, 0, stream>>>(hbuf, 1024, wA, b_f1, xz, MTOK, 4096, 1024);
  // 9. ffn2 + bias -> tmp (f32)          (N=1024,K=4096)
  cvt_k<<<2048, 256, 0, stream>>>(w_f2, wA, (4*DM*DM)/8);
  gemm_bt<4><<<dim3(8,64), 256, 0, stream>>>(xz, 4096, wA, b_f2, tmp, MTOK, 1024, 4096);
  // 10. out = rmsnorm(tmp + hbuf) * ffn_norm_w -> d_out (f32)
  add_rms_k<true,false><<<MTOK, 256, 0, stream>>>(tmp, hbuf, norm2, d_out);
}